// Round 1
// baseline (578.325 us; speedup 1.0000x reference)
//
#include <hip/hip_runtime.h>
#include <hip/hip_bf16.h>

#define NN 50000     // nodes
#define NR 4         // relations
#define NE 160000    // edges per relation
#define HD 128       // hidden dim
#define OD 100       // out dim
#define NQ 8192      // queries

typedef __attribute__((ext_vector_type(8))) short bf16x8;
typedef __attribute__((ext_vector_type(4))) float f32x4;
typedef __attribute__((ext_vector_type(4))) int int4v;

static __device__ __forceinline__ unsigned short f2bf(float f) {
    union { float f; unsigned int u; } v; v.f = f;
    unsigned int u = v.u;
    unsigned int r = u + 0x7FFFu + ((u >> 16) & 1u);   // RNE
    return (unsigned short)(r >> 16);
}

// ---------------- graph preprocessing ----------------

__global__ void zero_deg_kernel(int* __restrict__ deg) {
    int i = blockIdx.x * 256 + threadIdx.x;
    if (i < NR * NN) deg[i] = 0;
}

__global__ void count_deg_kernel(const int* __restrict__ edge_dst, int* __restrict__ deg) {
    int i = blockIdx.x * 256 + threadIdx.x;
    if (i < NR * NE) {
        int r = i / NE;
        atomicAdd(&deg[r * NN + edge_dst[i]], 1);
    }
}

__global__ __launch_bounds__(1024) void scan_deg_kernel(const int* __restrict__ deg,
                                                        int* __restrict__ row_start,
                                                        int* __restrict__ cursor) {
    const int r = blockIdx.x;
    const int tid = threadIdx.x;
    __shared__ int buf[1024];
    __shared__ int carry_s;
    if (tid == 0) carry_s = 0;
    __syncthreads();
    for (int base = 0; base < NN; base += 1024) {
        const int idx = base + tid;
        int v = (idx < NN) ? deg[r * NN + idx] : 0;
        buf[tid] = v;
        __syncthreads();
        int sum = v;
        for (int off = 1; off < 1024; off <<= 1) {
            int t = (tid >= off) ? buf[tid - off] : 0;
            __syncthreads();
            sum += t;
            buf[tid] = sum;
            __syncthreads();
        }
        const int carry = carry_s;
        const int excl = carry + sum - v;
        if (idx < NN) {
            row_start[r * (NN + 1) + idx] = excl;
            cursor[r * NN + idx] = excl;
        }
        __syncthreads();                 // all reads of carry_s done
        if (tid == 1023) carry_s = carry + buf[1023];
        __syncthreads();
    }
    if (tid == 0) row_start[r * (NN + 1) + NN] = carry_s;
}

__global__ void fill_csr_kernel(const int* __restrict__ edge_src,
                                const int* __restrict__ edge_dst,
                                int* __restrict__ cursor, int* __restrict__ csr_src) {
    int i = blockIdx.x * 256 + threadIdx.x;
    if (i < NR * NE) {
        int r = i / NE;
        int dst = edge_dst[i];
        int pos = atomicAdd(&cursor[r * NN + dst], 1);
        csr_src[r * NE + pos] = edge_src[i];
    }
}

__global__ void inv_deg_kernel(const int* __restrict__ deg, float* __restrict__ inv) {
    int i = blockIdx.x * 256 + threadIdx.x;
    if (i < NR * NN) inv[i] = 1.0f / fmaxf((float)deg[i], 1.0f);
}

// ---------------- weight / feature prep ----------------

__global__ void conv_feat_kernel(const float* __restrict__ f, unsigned short* __restrict__ h) {
    int i = (blockIdx.x * 256 + threadIdx.x) * 4;
    if (i < NN * HD) {
        h[i + 0] = f2bf(f[i + 0]);
        h[i + 1] = f2bf(f[i + 1]);
        h[i + 2] = f2bf(f[i + 2]);
        h[i + 3] = f2bf(f[i + 3]);
    }
}

// Wt [640][128] bf16: col c<128 -> Ws[k][c]; else r=(c-128)>>7, cc=(c-128)&127 -> Wr[r][k][cc]
__global__ void prep_w_hidden_kernel(const float* __restrict__ Ws, const float* __restrict__ Wr,
                                     unsigned short* __restrict__ Wt) {
    int c = blockIdx.x;     // 640
    int k = threadIdx.x;    // 128
    float v;
    if (c < HD) v = Ws[k * HD + c];
    else {
        int r = (c - HD) >> 7, cc = (c - HD) & 127;
        v = Wr[(r * HD + k) * HD + cc];
    }
    Wt[c * HD + k] = f2bf(v);
}

// Wt_o [512][128] bf16: c<100 -> Ws_o[k][c]; 100<=c<500 -> Wr_o[r][k][cc]; else 0
__global__ void prep_w_out_kernel(const float* __restrict__ Ws, const float* __restrict__ Wr,
                                  unsigned short* __restrict__ Wt) {
    int c = blockIdx.x;     // 512
    int k = threadIdx.x;    // 128
    float v = 0.0f;
    if (c < OD) v = Ws[k * OD + c];
    else if (c < 5 * OD) {
        int r = (c - OD) / OD, cc = (c - OD) % OD;
        v = Wr[(r * HD + k) * OD + cc];
    }
    Wt[c * HD + k] = f2bf(v);
}

// ---------------- GEMM: C[M][ldc] = A[M][128](bf16) @ Bt[ldc][128]^T (bf16) ----------------
// block 256 = 4 waves (2x2), block tile 128(M) x 64(N), wave tile 64x32, K=128 in 4 steps.

#define LDA_P 136

__global__ __launch_bounds__(256) void gemm_bf16_kernel(const unsigned short* __restrict__ A,
                                                        const unsigned short* __restrict__ Bt,
                                                        float* __restrict__ C,
                                                        int M, int ldc) {
    __shared__ unsigned short As[128 * LDA_P];
    const int m0 = blockIdx.x * 128;
    const int n0 = blockIdx.y * 64;
    const int tid = threadIdx.x;

    // stage A tile (128 rows x 256B) into LDS, coalesced 16B chunks
    for (int c = tid; c < 128 * 16; c += 256) {
        int row = c >> 4, cj = c & 15;
        int gr = m0 + row;
        if (gr >= M) gr = M - 1;                    // clamp; results masked on store
        int4v v = *(const int4v*)(A + gr * HD + cj * 8);
        *(int4v*)(&As[row * LDA_P + cj * 8]) = v;
    }
    __syncthreads();

    const int w = tid >> 6;
    const int lane = tid & 63;
    const int wm = (w & 1) * 64;
    const int wn = (w >> 1) * 32;
    const int lr = lane & 15;
    const int lg = lane >> 4;

    f32x4 acc[4][2];
#pragma unroll
    for (int mi = 0; mi < 4; mi++)
#pragma unroll
        for (int ni = 0; ni < 2; ni++) acc[mi][ni] = (f32x4){0.f, 0.f, 0.f, 0.f};

#pragma unroll
    for (int kk = 0; kk < 4; ++kk) {
        const int k0 = kk * 32 + lg * 8;
        bf16x8 a[4], b[2];
#pragma unroll
        for (int mi = 0; mi < 4; mi++)
            a[mi] = *(const bf16x8*)(&As[(wm + mi * 16 + lr) * LDA_P + k0]);
#pragma unroll
        for (int ni = 0; ni < 2; ni++)
            b[ni] = *(const bf16x8*)(Bt + (n0 + wn + ni * 16 + lr) * HD + k0);
#pragma unroll
        for (int mi = 0; mi < 4; mi++)
#pragma unroll
            for (int ni = 0; ni < 2; ni++)
                acc[mi][ni] = __builtin_amdgcn_mfma_f32_16x16x32_bf16(a[mi], b[ni], acc[mi][ni], 0, 0, 0);
    }

#pragma unroll
    for (int mi = 0; mi < 4; mi++) {
#pragma unroll
        for (int ni = 0; ni < 2; ni++) {
            const int col = n0 + wn + ni * 16 + lr;
#pragma unroll
            for (int j = 0; j < 4; j++) {
                const int row = m0 + wm + mi * 16 + lg * 4 + j;
                if (row < M) C[row * ldc + col] = acc[mi][ni][j];
            }
        }
    }
}

// ---------------- aggregation ----------------

// hidden: out bf16 h_next[n][128] = relu( Y[n][j] + sum_r inv_deg[r][n] * sum_e Y[src][128 + r*128 + j] )
__global__ __launch_bounds__(128) void agg_hidden_kernel(const float* __restrict__ Y,
                                                         const int* __restrict__ row_start,
                                                         const int* __restrict__ csr_src,
                                                         const float* __restrict__ inv_deg,
                                                         unsigned short* __restrict__ h_next) {
    const int n = blockIdx.x;
    const int j = threadIdx.x;
    float acc = Y[n * 640 + j];
#pragma unroll
    for (int r = 0; r < NR; r++) {
        const int s = row_start[r * (NN + 1) + n];
        const int e = row_start[r * (NN + 1) + n + 1];
        float sum = 0.f;
        for (int t = s; t < e; t++) {
            const int src = csr_src[r * NE + t];
            sum += Y[src * 640 + HD + (r << 7) + j];
        }
        acc += inv_deg[r * NN + n] * sum;
    }
    h_next[n * HD + j] = f2bf(fmaxf(acc, 0.f));
}

// output layer: h_out f32 [n][100], Y2 ldc=512, layout: 0..99 Ws, 100+r*100+j
__global__ __launch_bounds__(128) void agg_out_kernel(const float* __restrict__ Y,
                                                      const int* __restrict__ row_start,
                                                      const int* __restrict__ csr_src,
                                                      const float* __restrict__ inv_deg,
                                                      float* __restrict__ h_out) {
    const int n = blockIdx.x;
    const int j = threadIdx.x;
    if (j >= OD) return;
    float acc = Y[n * 512 + j];
#pragma unroll
    for (int r = 0; r < NR; r++) {
        const int s = row_start[r * (NN + 1) + n];
        const int e = row_start[r * (NN + 1) + n + 1];
        float sum = 0.f;
        for (int t = s; t < e; t++) {
            const int src = csr_src[r * NE + t];
            sum += Y[src * 512 + OD + r * OD + j];
        }
        acc += inv_deg[r * NN + n] * sum;
    }
    h_out[n * OD + j] = acc;
}

__global__ __launch_bounds__(128) void gather_out_kernel(const float* __restrict__ h_out,
                                                         const int* __restrict__ head,
                                                         const int* __restrict__ tail,
                                                         float* __restrict__ out) {
    const int q = blockIdx.x;
    const int j = threadIdx.x;
    if (j >= OD) return;
    out[q * OD + j] = h_out[head[q] * OD + j];
    out[NQ * OD + q * OD + j] = h_out[tail[q] * OD + j];
}

// ---------------- launch ----------------

extern "C" void kernel_launch(void* const* d_in, const int* in_sizes, int n_in,
                              void* d_out, int out_size, void* d_ws, size_t ws_size,
                              hipStream_t stream) {
    const float* feature = (const float*)d_in[0];
    const float* Wr_h    = (const float*)d_in[1];   // [2][4][128][128]
    const float* Ws_h    = (const float*)d_in[2];   // [2][128][128]
    const float* Wr_o    = (const float*)d_in[3];   // [4][128][100]
    const float* Ws_o    = (const float*)d_in[4];   // [128][100]
    const int* edge_src  = (const int*)d_in[5];
    const int* edge_dst  = (const int*)d_in[6];
    const int* head_idx  = (const int*)d_in[7];
    const int* tail_idx  = (const int*)d_in[8];
    float* out = (float*)d_out;

    char* ws = (char*)d_ws;
    size_t off = 0;
    auto alloc = [&](size_t bytes) -> void* {
        void* p = ws + off;
        off += (bytes + 255) & ~(size_t)255;
        return p;
    };
    float*          Y    = (float*)alloc((size_t)NN * 640 * 4);
    unsigned short* hA   = (unsigned short*)alloc((size_t)NN * HD * 2);
    unsigned short* hB   = (unsigned short*)alloc((size_t)NN * HD * 2);
    float*          hOut = (float*)alloc((size_t)NN * OD * 4);
    unsigned short* WtH0 = (unsigned short*)alloc(640 * HD * 2);
    unsigned short* WtH1 = (unsigned short*)alloc(640 * HD * 2);
    unsigned short* WtO  = (unsigned short*)alloc(512 * HD * 2);
    int*            deg  = (int*)alloc((size_t)NR * NN * 4);
    float*          inv  = (float*)alloc((size_t)NR * NN * 4);
    int*            rowS = (int*)alloc((size_t)NR * (NN + 1) * 4);
    int*            curs = (int*)alloc((size_t)NR * NN * 4);
    int*            csrS = (int*)alloc((size_t)NR * NE * 4);
    (void)ws_size;

    // graph prep
    zero_deg_kernel<<<(NR * NN + 255) / 256, 256, 0, stream>>>(deg);
    count_deg_kernel<<<(NR * NE + 255) / 256, 256, 0, stream>>>(edge_dst, deg);
    scan_deg_kernel<<<NR, 1024, 0, stream>>>(deg, rowS, curs);
    fill_csr_kernel<<<(NR * NE + 255) / 256, 256, 0, stream>>>(edge_src, edge_dst, curs, csrS);
    inv_deg_kernel<<<(NR * NN + 255) / 256, 256, 0, stream>>>(deg, inv);

    // weight / feature prep
    conv_feat_kernel<<<(NN * HD / 4 + 255) / 256, 256, 0, stream>>>(feature, hA);
    prep_w_hidden_kernel<<<640, 128, 0, stream>>>(Ws_h, Wr_h, WtH0);
    prep_w_hidden_kernel<<<640, 128, 0, stream>>>(Ws_h + HD * HD, Wr_h + NR * HD * HD, WtH1);
    prep_w_out_kernel<<<512, 128, 0, stream>>>(Ws_o, Wr_o, WtO);

    const int mblocks = (NN + 127) / 128;   // 391

    // layer 0: hA -> Y -> hB
    gemm_bf16_kernel<<<dim3(mblocks, 10), 256, 0, stream>>>(hA, WtH0, Y, NN, 640);
    agg_hidden_kernel<<<NN, 128, 0, stream>>>(Y, rowS, csrS, inv, hB);

    // layer 1: hB -> Y -> hA
    gemm_bf16_kernel<<<dim3(mblocks, 10), 256, 0, stream>>>(hB, WtH1, Y, NN, 640);
    agg_hidden_kernel<<<NN, 128, 0, stream>>>(Y, rowS, csrS, inv, hA);

    // output layer: hA -> Y(512) -> hOut
    gemm_bf16_kernel<<<dim3(mblocks, 8), 256, 0, stream>>>(hA, WtO, Y, NN, 512);
    agg_out_kernel<<<NN, 128, 0, stream>>>(Y, rowS, csrS, inv, hOut);

    // final gather
    gather_out_kernel<<<NQ, 128, 0, stream>>>(hOut, head_idx, tail_idx, out);
}

// Round 2
// 377.345 us; speedup vs baseline: 1.5326x; 1.5326x over previous
//
#include <hip/hip_runtime.h>
#include <hip/hip_bf16.h>

#define NN 50000     // nodes
#define NR 4         // relations
#define NE 160000    // edges per relation
#define HD 128       // hidden dim
#define OD 100       // out dim
#define NQ 8192      // queries
#define NB_SCAN 196  // 196*256 >= NN

typedef __attribute__((ext_vector_type(8))) short bf16x8;
typedef __attribute__((ext_vector_type(4))) float f32x4;
typedef __attribute__((ext_vector_type(4))) int int4v;

static __device__ __forceinline__ unsigned short f2bf(float f) {
    union { float f; unsigned int u; } v; v.f = f;
    unsigned int u = v.u;
    unsigned int r = u + 0x7FFFu + ((u >> 16) & 1u);   // RNE
    return (unsigned short)(r >> 16);
}
static __device__ __forceinline__ float bflo(unsigned int v) {
    union { unsigned int u; float f; } x; x.u = v << 16; return x.f;
}
static __device__ __forceinline__ float bfhi(unsigned int v) {
    union { unsigned int u; float f; } x; x.u = v & 0xffff0000u; return x.f;
}

// ---------------- graph preprocessing ----------------

__global__ void zero_deg_kernel(int* __restrict__ deg) {
    int i = blockIdx.x * 256 + threadIdx.x;
    if (i < NR * NN) deg[i] = 0;
}

__global__ void count_deg_kernel(const int* __restrict__ edge_dst, int* __restrict__ deg) {
    int i = blockIdx.x * 256 + threadIdx.x;
    if (i < NR * NE) {
        int r = i / NE;
        atomicAdd(&deg[r * NN + edge_dst[i]], 1);
    }
}

// Phase A: per-256-chunk exclusive scan + chunk sums
__global__ __launch_bounds__(256) void scanA_kernel(const int* __restrict__ deg,
                                                    int* __restrict__ excl,
                                                    int* __restrict__ bsum) {
    const int r = blockIdx.x / NB_SCAN;
    const int b = blockIdx.x % NB_SCAN;
    const int tid = threadIdx.x;
    const int idx = b * 256 + tid;
    int v = (idx < NN) ? deg[r * NN + idx] : 0;
    __shared__ int buf[256];
    buf[tid] = v; __syncthreads();
    int sum = v;
    for (int off = 1; off < 256; off <<= 1) {
        int t = (tid >= off) ? buf[tid - off] : 0;
        __syncthreads();
        sum += t; buf[tid] = sum;
        __syncthreads();
    }
    if (idx < NN) excl[r * NN + idx] = sum - v;
    if (tid == 255) bsum[r * NB_SCAN + b] = sum;
}

// Phase B: exclusive scan of the 196 chunk sums per relation
__global__ __launch_bounds__(256) void scanB_kernel(int* __restrict__ bsum) {
    const int r = blockIdx.x;
    const int tid = threadIdx.x;
    int v = (tid < NB_SCAN) ? bsum[r * NB_SCAN + tid] : 0;
    __shared__ int buf[256];
    buf[tid] = v; __syncthreads();
    int sum = v;
    for (int off = 1; off < 256; off <<= 1) {
        int t = (tid >= off) ? buf[tid - off] : 0;
        __syncthreads();
        sum += t; buf[tid] = sum;
        __syncthreads();
    }
    if (tid < NB_SCAN) bsum[r * NB_SCAN + tid] = sum - v;
}

// Phase C: combine, write row_start + cursor
__global__ __launch_bounds__(256) void scanC_kernel(const int* __restrict__ excl,
                                                    const int* __restrict__ bsum,
                                                    int* __restrict__ row_start,
                                                    int* __restrict__ cursor) {
    const int r = blockIdx.x / NB_SCAN;
    const int b = blockIdx.x % NB_SCAN;
    const int idx = b * 256 + threadIdx.x;
    if (idx < NN) {
        int v = excl[r * NN + idx] + bsum[r * NB_SCAN + b];
        row_start[r * (NN + 1) + idx] = v;
        cursor[r * NN + idx] = v;
    }
    if (b == 0 && threadIdx.x == 0) row_start[r * (NN + 1) + NN] = NE;
}

__global__ void fill_csr_kernel(const int* __restrict__ edge_src,
                                const int* __restrict__ edge_dst,
                                int* __restrict__ cursor, int* __restrict__ csr_src) {
    int i = blockIdx.x * 256 + threadIdx.x;
    if (i < NR * NE) {
        int r = i / NE;
        int dst = edge_dst[i];
        int pos = atomicAdd(&cursor[r * NN + dst], 1);
        csr_src[r * NE + pos] = edge_src[i];
    }
}

__global__ void inv_deg_kernel(const int* __restrict__ deg, float* __restrict__ inv) {
    int i = blockIdx.x * 256 + threadIdx.x;
    if (i < NR * NN) inv[i] = 1.0f / fmaxf((float)deg[i], 1.0f);
}

// ---------------- weight / feature prep ----------------

__global__ void conv_feat_kernel(const float* __restrict__ f, unsigned short* __restrict__ h) {
    int i = (blockIdx.x * 256 + threadIdx.x) * 4;
    if (i < NN * HD) {
        h[i + 0] = f2bf(f[i + 0]);
        h[i + 1] = f2bf(f[i + 1]);
        h[i + 2] = f2bf(f[i + 2]);
        h[i + 3] = f2bf(f[i + 3]);
    }
}

// Wt [640][128] bf16: col c<128 -> Ws[k][c]; else r=(c-128)>>7, cc=(c-128)&127 -> Wr[r][k][cc]
__global__ void prep_w_hidden_kernel(const float* __restrict__ Ws, const float* __restrict__ Wr,
                                     unsigned short* __restrict__ Wt) {
    int c = blockIdx.x;     // 640
    int k = threadIdx.x;    // 128
    float v;
    if (c < HD) v = Ws[k * HD + c];
    else {
        int r = (c - HD) >> 7, cc = (c - HD) & 127;
        v = Wr[(r * HD + k) * HD + cc];
    }
    Wt[c * HD + k] = f2bf(v);
}

// Wt_o [512][128] bf16: c<100 -> Ws_o[k][c]; 100<=c<500 -> Wr_o[r][k][cc]; else 0
__global__ void prep_w_out_kernel(const float* __restrict__ Ws, const float* __restrict__ Wr,
                                  unsigned short* __restrict__ Wt) {
    int c = blockIdx.x;     // 512
    int k = threadIdx.x;    // 128
    float v = 0.0f;
    if (c < OD) v = Ws[k * OD + c];
    else if (c < 5 * OD) {
        int r = (c - OD) / OD, cc = (c - OD) % OD;
        v = Wr[(r * HD + k) * OD + cc];
    }
    Wt[c * HD + k] = f2bf(v);
}

// ---------------- GEMM: Y[M][ldc](bf16) = A[M][128](bf16) @ Bt[ldc][128]^T (bf16) ----------------
// block 256 = 4 waves (2x2), block tile 128(M) x 64(N), wave tile 64x32, K=128 in 4 steps.

#define LDA_P 136

__global__ __launch_bounds__(256) void gemm_bf16_kernel(const unsigned short* __restrict__ A,
                                                        const unsigned short* __restrict__ Bt,
                                                        unsigned short* __restrict__ Y,
                                                        int M, int ldc) {
    __shared__ unsigned short As[128 * LDA_P];
    const int m0 = blockIdx.x * 128;
    const int n0 = blockIdx.y * 64;
    const int tid = threadIdx.x;

    // stage A tile (128 rows x 256B) into LDS, coalesced 16B chunks
    for (int c = tid; c < 128 * 16; c += 256) {
        int row = c >> 4, cj = c & 15;
        int gr = m0 + row;
        if (gr >= M) gr = M - 1;                    // clamp; results masked on store
        int4v v = *(const int4v*)(A + gr * HD + cj * 8);
        *(int4v*)(&As[row * LDA_P + cj * 8]) = v;
    }
    __syncthreads();

    const int w = tid >> 6;
    const int lane = tid & 63;
    const int wm = (w & 1) * 64;
    const int wn = (w >> 1) * 32;
    const int lr = lane & 15;
    const int lg = lane >> 4;

    f32x4 acc[4][2];
#pragma unroll
    for (int mi = 0; mi < 4; mi++)
#pragma unroll
        for (int ni = 0; ni < 2; ni++) acc[mi][ni] = (f32x4){0.f, 0.f, 0.f, 0.f};

#pragma unroll
    for (int kk = 0; kk < 4; ++kk) {
        const int k0 = kk * 32 + lg * 8;
        bf16x8 a[4], b[2];
#pragma unroll
        for (int mi = 0; mi < 4; mi++)
            a[mi] = *(const bf16x8*)(&As[(wm + mi * 16 + lr) * LDA_P + k0]);
#pragma unroll
        for (int ni = 0; ni < 2; ni++)
            b[ni] = *(const bf16x8*)(Bt + (n0 + wn + ni * 16 + lr) * HD + k0);
#pragma unroll
        for (int mi = 0; mi < 4; mi++)
#pragma unroll
            for (int ni = 0; ni < 2; ni++)
                acc[mi][ni] = __builtin_amdgcn_mfma_f32_16x16x32_bf16(a[mi], b[ni], acc[mi][ni], 0, 0, 0);
    }

#pragma unroll
    for (int mi = 0; mi < 4; mi++) {
#pragma unroll
        for (int ni = 0; ni < 2; ni++) {
            const int col = n0 + wn + ni * 16 + lr;
#pragma unroll
            for (int j = 0; j < 4; j++) {
                const int row = m0 + wm + mi * 16 + lg * 4 + j;
                if (row < M) Y[row * ldc + col] = f2bf(acc[mi][ni][j]);
            }
        }
    }
}

// ---------------- aggregation ----------------
// One 64-lane wave per node; lane owns 2 columns (ushort2). 4 nodes per 256-block.

__global__ __launch_bounds__(256) void agg_hidden_kernel(const unsigned short* __restrict__ Y,
                                                         const int* __restrict__ row_start,
                                                         const int* __restrict__ csr_src,
                                                         const float* __restrict__ inv_deg,
                                                         unsigned short* __restrict__ h_next) {
    const int n = blockIdx.x * 4 + (threadIdx.x >> 6);
    const int lane = threadIdx.x & 63;
    const int j0 = lane * 2;

    unsigned int sv = *(const unsigned int*)(Y + n * 640 + j0);
    float a0 = bflo(sv), a1 = bfhi(sv);

#pragma unroll
    for (int r = 0; r < NR; r++) {
        const int s = row_start[r * (NN + 1) + n];
        const int e = row_start[r * (NN + 1) + n + 1];
        const unsigned short* __restrict__ Yr = Y + HD + (r << 7) + j0;
        float s0 = 0.f, s1 = 0.f;
        int t = s;
        for (; t + 2 <= e; t += 2) {
            const int i0 = csr_src[r * NE + t];
            const int i1 = csr_src[r * NE + t + 1];
            unsigned int v0 = *(const unsigned int*)(Yr + i0 * 640);
            unsigned int v1 = *(const unsigned int*)(Yr + i1 * 640);
            s0 += bflo(v0) + bflo(v1);
            s1 += bfhi(v0) + bfhi(v1);
        }
        if (t < e) {
            const int i0 = csr_src[r * NE + t];
            unsigned int v0 = *(const unsigned int*)(Yr + i0 * 640);
            s0 += bflo(v0);
            s1 += bfhi(v0);
        }
        const float w = inv_deg[r * NN + n];
        a0 += w * s0;
        a1 += w * s1;
    }
    unsigned int packed = (unsigned int)f2bf(fmaxf(a0, 0.f)) |
                          ((unsigned int)f2bf(fmaxf(a1, 0.f)) << 16);
    *(unsigned int*)(h_next + n * HD + j0) = packed;
}

// output layer: h_out f32 [n][100], Y ldc=512 bf16, layout: 0..99 Ws, 100+r*100+j
__global__ __launch_bounds__(256) void agg_out_kernel(const unsigned short* __restrict__ Y,
                                                      const int* __restrict__ row_start,
                                                      const int* __restrict__ csr_src,
                                                      const float* __restrict__ inv_deg,
                                                      float* __restrict__ h_out) {
    const int n = blockIdx.x * 4 + (threadIdx.x >> 6);
    const int lane = threadIdx.x & 63;
    if (lane >= 50) return;
    const int j0 = lane * 2;

    unsigned int sv = *(const unsigned int*)(Y + n * 512 + j0);
    float a0 = bflo(sv), a1 = bfhi(sv);

#pragma unroll
    for (int r = 0; r < NR; r++) {
        const int s = row_start[r * (NN + 1) + n];
        const int e = row_start[r * (NN + 1) + n + 1];
        const unsigned short* __restrict__ Yr = Y + OD + r * OD + j0;
        float s0 = 0.f, s1 = 0.f;
        int t = s;
        for (; t + 2 <= e; t += 2) {
            const int i0 = csr_src[r * NE + t];
            const int i1 = csr_src[r * NE + t + 1];
            unsigned int v0 = *(const unsigned int*)(Yr + i0 * 512);
            unsigned int v1 = *(const unsigned int*)(Yr + i1 * 512);
            s0 += bflo(v0) + bflo(v1);
            s1 += bfhi(v0) + bfhi(v1);
        }
        if (t < e) {
            const int i0 = csr_src[r * NE + t];
            unsigned int v0 = *(const unsigned int*)(Yr + i0 * 512);
            s0 += bflo(v0);
            s1 += bfhi(v0);
        }
        const float w = inv_deg[r * NN + n];
        a0 += w * s0;
        a1 += w * s1;
    }
    float2 res = {a0, a1};
    *(float2*)(h_out + n * OD + j0) = res;
}

__global__ __launch_bounds__(128) void gather_out_kernel(const float* __restrict__ h_out,
                                                         const int* __restrict__ head,
                                                         const int* __restrict__ tail,
                                                         float* __restrict__ out) {
    const int q = blockIdx.x;
    const int j = threadIdx.x;
    if (j >= OD) return;
    out[q * OD + j] = h_out[head[q] * OD + j];
    out[NQ * OD + q * OD + j] = h_out[tail[q] * OD + j];
}

// ---------------- launch ----------------

extern "C" void kernel_launch(void* const* d_in, const int* in_sizes, int n_in,
                              void* d_out, int out_size, void* d_ws, size_t ws_size,
                              hipStream_t stream) {
    const float* feature = (const float*)d_in[0];
    const float* Wr_h    = (const float*)d_in[1];   // [2][4][128][128]
    const float* Ws_h    = (const float*)d_in[2];   // [2][128][128]
    const float* Wr_o    = (const float*)d_in[3];   // [4][128][100]
    const float* Ws_o    = (const float*)d_in[4];   // [128][100]
    const int* edge_src  = (const int*)d_in[5];
    const int* edge_dst  = (const int*)d_in[6];
    const int* head_idx  = (const int*)d_in[7];
    const int* tail_idx  = (const int*)d_in[8];
    float* out = (float*)d_out;

    char* ws = (char*)d_ws;
    size_t off = 0;
    auto alloc = [&](size_t bytes) -> void* {
        void* p = ws + off;
        off += (bytes + 255) & ~(size_t)255;
        return p;
    };
    unsigned short* Y    = (unsigned short*)alloc((size_t)NN * 640 * 2);
    unsigned short* hA   = (unsigned short*)alloc((size_t)NN * HD * 2);
    unsigned short* hB   = (unsigned short*)alloc((size_t)NN * HD * 2);
    float*          hOut = (float*)alloc((size_t)NN * OD * 4);
    unsigned short* WtH0 = (unsigned short*)alloc(640 * HD * 2);
    unsigned short* WtH1 = (unsigned short*)alloc(640 * HD * 2);
    unsigned short* WtO  = (unsigned short*)alloc(512 * HD * 2);
    int*            deg  = (int*)alloc((size_t)NR * NN * 4);
    float*          inv  = (float*)alloc((size_t)NR * NN * 4);
    int*            rowS = (int*)alloc((size_t)NR * (NN + 1) * 4);
    int*            curs = (int*)alloc((size_t)NR * NN * 4);
    int*            csrS = (int*)alloc((size_t)NR * NE * 4);
    int*            excl = (int*)alloc((size_t)NR * NN * 4);
    int*            bsum = (int*)alloc((size_t)NR * NB_SCAN * 4);
    (void)ws_size;

    // graph prep
    zero_deg_kernel<<<(NR * NN + 255) / 256, 256, 0, stream>>>(deg);
    count_deg_kernel<<<(NR * NE + 255) / 256, 256, 0, stream>>>(edge_dst, deg);
    scanA_kernel<<<NR * NB_SCAN, 256, 0, stream>>>(deg, excl, bsum);
    scanB_kernel<<<NR, 256, 0, stream>>>(bsum);
    scanC_kernel<<<NR * NB_SCAN, 256, 0, stream>>>(excl, bsum, rowS, curs);
    fill_csr_kernel<<<(NR * NE + 255) / 256, 256, 0, stream>>>(edge_src, edge_dst, curs, csrS);
    inv_deg_kernel<<<(NR * NN + 255) / 256, 256, 0, stream>>>(deg, inv);

    // weight / feature prep
    conv_feat_kernel<<<(NN * HD / 4 + 255) / 256, 256, 0, stream>>>(feature, hA);
    prep_w_hidden_kernel<<<640, 128, 0, stream>>>(Ws_h, Wr_h, WtH0);
    prep_w_hidden_kernel<<<640, 128, 0, stream>>>(Ws_h + HD * HD, Wr_h + NR * HD * HD, WtH1);
    prep_w_out_kernel<<<512, 128, 0, stream>>>(Ws_o, Wr_o, WtO);

    const int mblocks = (NN + 127) / 128;   // 391

    // layer 0: hA -> Y -> hB
    gemm_bf16_kernel<<<dim3(mblocks, 10), 256, 0, stream>>>(hA, WtH0, Y, NN, 640);
    agg_hidden_kernel<<<NN / 4, 256, 0, stream>>>(Y, rowS, csrS, inv, hB);

    // layer 1: hB -> Y -> hA
    gemm_bf16_kernel<<<dim3(mblocks, 10), 256, 0, stream>>>(hB, WtH1, Y, NN, 640);
    agg_hidden_kernel<<<NN / 4, 256, 0, stream>>>(Y, rowS, csrS, inv, hA);

    // output layer: hA -> Y(512) -> hOut
    gemm_bf16_kernel<<<dim3(mblocks, 8), 256, 0, stream>>>(hA, WtO, Y, NN, 512);
    agg_out_kernel<<<NN / 4, 256, 0, stream>>>(Y, rowS, csrS, inv, hOut);

    // final gather
    gather_out_kernel<<<NQ, 128, 0, stream>>>(hOut, head_idx, tail_idx, out);
}